// Round 12
// baseline (3518488.281 us; speedup 1.0000x reference)
//
#include <hip/hip_runtime.h>

// Persistent LSTM autoencoder V4: XCD-derived groups, L2-local exchange.
// Groups are NOT assumed from blockIdx: each block reads HW_REG_XCC_ID and
// self-assigns a role slot on its own XCD via an atomic counter. With 256
// blocks at 1/CU (forced by >80KB LDS), each XCD hosts exactly its 32 CUs'
// blocks -> every group is same-L2 by construction.
// Exchange: plain write-through h stores + plain loads on fresh per-step
// buffers (R10-proven) + sc0 flag polls. All L2-speed, no L3 round trips.

#define Bsz 512
#define Tsz 128
#define Esz 256
#define Hsz 512
#define Zsz 256
#define NG  2048                 // 4*Hsz gate columns, interleaved n = 4*j + gate
#define BUFE (64 * 512 * 8)      // f16 elements per h step-buffer (512 KB)

typedef _Float16 f16;
typedef unsigned long long ull;
typedef __attribute__((ext_vector_type(8))) _Float16 f16x8;
typedef __attribute__((ext_vector_type(4))) float f32x4;
typedef __attribute__((ext_vector_type(4))) int i32x4;

__device__ __forceinline__ float sigm(float x) { return 1.0f / (1.0f + __expf(-x)); }
__device__ __forceinline__ float tanh_f(float x) { return __builtin_fmaf(2.f, sigm(2.f * x), -1.f); }
__device__ __forceinline__ int swz(int kd, int r) {
    return (kd & ~56) | ((((kd >> 3) & 7) ^ (r & 7)) << 3);
}
__device__ __forceinline__ void gld16(const void* g, void* l) {
    __builtin_amdgcn_global_load_lds(
        (const __attribute__((address_space(1))) unsigned*)g,
        (__attribute__((address_space(3))) unsigned*)l, 16, 0, 0);
}
__device__ __forceinline__ f16x8 asfrag(i32x4 a) {
    union { i32x4 u; f16x8 v; } x; x.u = a; return x.v;
}
// sc0 load: bypasses L1, served by this XCD's L2 (where same-XCD producers'
// write-through stores land). Proven-to-assemble form from R8.
__device__ __forceinline__ unsigned ld32_sc0(const unsigned* p) {
    unsigned r;
    asm volatile("global_load_dword %0, %1, off sc0\n\ts_waitcnt vmcnt(0)"
                 : "=v"(r) : "v"(p) : "memory");
    return r;
}

// ---------------------------------------------------------------------------
__global__ __launch_bounds__(256) void prep_kernel(
    const float* __restrict__ x,
    const float* __restrict__ enc_W_ih, const float* __restrict__ enc_W_hh,
    const float* __restrict__ enc_b_ih, const float* __restrict__ enc_b_hh,
    const float* __restrict__ dec_W_ih, const float* __restrict__ dec_W_hh,
    const float* __restrict__ dec_b_ih, const float* __restrict__ dec_b_hh,
    const float* __restrict__ z_W,
    f16* __restrict__ xe,    f16* __restrict__ eih_s, f16* __restrict__ ehh_s,
    f16* __restrict__ dhh_p, f16* __restrict__ wsm_s, f16* __restrict__ zw_s,
    float* __restrict__ encB, float* __restrict__ decB, float* __restrict__ decB0,
    f16* __restrict__ hb, unsigned* __restrict__ flags)
{
    const int tid = blockIdx.x * 256 + threadIdx.x;   // 512 blocks
    const int NT  = 512 * 256;

    for (int i = tid; i < 262160; i += NT) flags[i] = 0;   // flags + xcd ctrs
    for (int i = tid; i < BUFE; i += NT) hb[i] = (f16)0.1f;   // h_0

    // xe[((t*32 + g)*512 + b)*8 + e] = x[b][t][g*8 + e]
    for (int i = tid; i < Bsz * Tsz * Esz; i += NT) {
        const int e = i & 7, b = (i >> 3) & 511, g = (i >> 12) & 31, t = i >> 17;
        xe[i] = (f16)x[((size_t)b * Tsz + t) * Esz + g * 8 + e];
    }
    // enc W_ih: [NG][E], swizzled
    for (int i = tid; i < NG * Esz; i += NT) {
        const int n = i >> 8, kd = i & 255;
        const int sr = (n & 3) * Hsz + (n >> 2);
        eih_s[i] = (f16)enc_W_ih[sr * Esz + swz(kd, n)];
    }
    // [NG][H] family
    for (int i = tid; i < NG * Hsz; i += NT) {
        const int n = i >> 9, kd = i & 511;
        const int sr = (n & 3) * Hsz + (n >> 2);
        const int ks = swz(kd, n);
        ehh_s[i] = (f16)enc_W_hh[sr * Hsz + ks];
        wsm_s[i] = (f16)(dec_W_ih[sr * Hsz + ks] + dec_W_hh[sr * Hsz + ks]);
        dhh_p[i] = (f16)dec_W_hh[sr * Hsz + kd];          // plain layout
    }
    // z_W: [Z][H], swizzled
    for (int i = tid; i < Zsz * Hsz; i += NT) {
        const int n = i >> 9, kd = i & 511;
        zw_s[i] = (f16)z_W[n * Hsz + swz(kd, n)];
    }

    const int wave = tid >> 6, lane = tid & 63;   // 2048 waves exactly
    if (wave < NG) {
        const int sr = (wave & 3) * Hsz + (wave >> 2);
        float s = 0.f;
        for (int k = lane; k < Hsz; k += 64) s += dec_W_ih[sr * Hsz + k];
        for (int off = 32; off; off >>= 1) s += __shfl_down(s, off);
        if (lane == 0) {
            encB[wave] = enc_b_ih[sr] + enc_b_hh[sr];
            const float bi = dec_b_ih[sr] + dec_b_hh[sr];
            decB[wave]  = bi;
            decB0[wave] = bi + 0.1f * s;
        }
    }
}

// ---------------------------------------------------------------------------
// Persistent phase. 256 blocks x 256 thr, 1/CU (LDS-forced).
// Role: bx = OWN XCD id (rows [bx*64,+64)); ny = slot from per-XCD atomic
// counter (gate cols [ny*64,+64)). All group traffic is same-XCD -> L2.
// ---------------------------------------------------------------------------
template <bool ENC>
__global__ __launch_bounds__(256, 1) void persist_kernel(
    const f16* __restrict__ xe, const f16* __restrict__ WihS,
    const f16* __restrict__ BhS, const f16* __restrict__ DhhP,
    const float* __restrict__ biasA, const float* __restrict__ biasB,
    f16* __restrict__ hb, float* __restrict__ cbuf,
    unsigned* __restrict__ flagbase, unsigned* __restrict__ ctrp)
{
    __shared__ __align__(16) f16 Bh[8 * 4096];                  // 64KB
    __shared__ __align__(16) f16 Wih[ENC ? 4 * 4096 : 8];       // 32KB enc
    __shared__ __align__(16) float xch[4][4 * 272];             // 17KB
    __shared__ __align__(16) f16 hx[4][256];                    // 2KB
    __shared__ __align__(16) f16 ldspad[ENC ? 8 : 2048];        // dec: push >80KB
    __shared__ unsigned roleS;

    const int tid = threadIdx.x;
    const int lane = tid & 63, w = tid >> 6;
    const int lr = lane & 15, lkb = lane >> 4;
    const int wm = (w & 1) * 32, wn = (w >> 1) * 32;
    const int rl = lane >> 3, kc = (lane & 7) * 8;

    // ---- derive role from ACTUAL placement ----
    unsigned xcd;
    asm("s_getreg_b32 %0, hwreg(HW_REG_XCC_ID)" : "=s"(xcd));
    xcd &= 7;
    if (tid == 0)
        roleS = __hip_atomic_fetch_add(&ctrp[xcd], 1u,
                                       __ATOMIC_RELAXED, __HIP_MEMORY_SCOPE_AGENT);
    if (tid == 0 && ldspad[0] != (f16)0) ldspad[1] = ldspad[0];  // keep pad alive
    __syncthreads();
    const int bx = (int)xcd, ny = (int)(roleS & 31);
    const int b0 = bx * 64, n0 = ny * 64;

    // ---- stage read-only B tiles into LDS (once per phase) ----
#pragma unroll
    for (int kt = 0; kt < 8; ++kt)
#pragma unroll
        for (int s2 = 0; s2 < 2; ++s2) {
            const int g = w + s2 * 4, row = g * 8 + rl;
            gld16(BhS + (size_t)(n0 + row) * Hsz + kt * 64 + kc, &Bh[kt * 4096 + g * 512]);
        }
    if (ENC) {
#pragma unroll
        for (int kt = 0; kt < 4; ++kt)
#pragma unroll
            for (int s2 = 0; s2 < 2; ++s2) {
                const int g = w + s2 * 4, row = g * 8 + rl;
                gld16(WihS + (size_t)(n0 + row) * Esz + kt * 64 + kc, &Wih[kt * 4096 + g * 512]);
            }
    }

    float bvA[2], bvB[2];
#pragma unroll
    for (int j = 0; j < 2; ++j) {
        bvA[j] = biasA[n0 + wn + j * 16 + lr];
        bvB[j] = ENC ? 0.f : biasB[n0 + wn + j * 16 + lr];
    }
    // c: registers across all steps; handoff slot keyed by role (phase-stable)
    const size_t cbase = (((size_t)ny * 8 + bx) * 256 + tid) * 4;
    float cc[4];
    if (ENC) { cc[0] = cc[1] = cc[2] = cc[3] = 0.1f; }
    else {
        const float4 cv = *(const float4*)&cbuf[cbase];
        cc[0] = cv.x; cc[1] = cv.y; cc[2] = cv.z; cc[3] = cv.w;
    }

    asm volatile("s_waitcnt vmcnt(0)" ::: "memory");
    __syncthreads();   // B tiles visible; last block barrier of the kernel

    unsigned* fbase = flagbase + (size_t)bx * (128 * 128);  // [t][128 waves]

    float* xc  = &xch[w][0];
    f16*  hxw = &hx[w][0];

#pragma unroll 1
    for (int t = 0; t < Tsz; ++t) {
        const f16* hsrc = ENC ? (hb + (size_t)t * BUFE)
                              : (t == 0 ? hb + (size_t)128 * BUFE
                                        : hb + (size_t)(t - 1) * BUFE);
        f16* hdst = ENC ? (hb + (size_t)(t + 1) * BUFE) : (hb + (size_t)t * BUFE);

        f32x4 acc[2][2];
#pragma unroll
        for (int j = 0; j < 2; ++j) {
            const float bv = (!ENC && t == 0) ? bvB[j] : bvA[j];
            acc[0][j] = (f32x4){bv, bv, bv, bv};
            acc[1][j] = acc[0][j];
        }

        // ---- enc: x A-frags + x-part MFMA BEFORE the wait ----
        if (ENC) {
            i32x4 ax[2][8];
#pragma unroll
            for (int i = 0; i < 2; ++i)
#pragma unroll
                for (int s = 0; s < 8; ++s)
                    ax[i][s] = *(const i32x4*)(xe +
                        (((size_t)(t * 32 + s * 4 + lkb)) * 512 + b0 + wm + i * 16 + lr) * 8);
#pragma unroll
            for (int s = 0; s < 8; ++s) {
                f16x8 bq[2];
#pragma unroll
                for (int j = 0; j < 2; ++j) {
                    const int rb = wn + j * 16 + lr;
                    bq[j] = *(const f16x8*)&Wih[(s >> 1) * 4096 + rb * 64 +
                                                ((((s & 1) * 4 + lkb) ^ (rb & 7)) * 8)];
                }
#pragma unroll
                for (int i = 0; i < 2; ++i)
#pragma unroll
                    for (int j = 0; j < 2; ++j)
                        acc[i][j] = __builtin_amdgcn_mfma_f32_16x16x32_f16(
                            asfrag(ax[i][s]), bq[j], acc[i][j], 0, 0, 0);
            }
        }

        // ---- wait for previous step's 128 producer waves (sc0, L2-served) ----
        if (t > 0) {
            const unsigned* fl = fbase + (size_t)(t - 1) * 128;
#pragma unroll
            for (int q = 0; q < 2; ++q) {
                const unsigned* p = fl + lane + q * 64;
                int it = 0;
                while (ld32_sc0(p) == 0 && it < (1 << 18)) {
                    __builtin_amdgcn_s_sleep(1); ++it;
                }
            }
        }

        // ---- h A-frags: PLAIN 16B loads (fresh addresses; L2-hit) ----
        i32x4 ah[2][16];
#pragma unroll
        for (int i = 0; i < 2; ++i)
#pragma unroll
            for (int s = 0; s < 16; ++s)
                ah[i][s] = *(const i32x4*)(hsrc +
                    (((size_t)(s * 4 + lkb)) * 512 + b0 + wm + i * 16 + lr) * 8);

        // ---- h-part MFMA (LDS B; dec t=0 reads dhh from global) ----
        if (!ENC && t == 0) {
#pragma unroll
            for (int s = 0; s < 16; ++s) {
                f16x8 bq[2];
#pragma unroll
                for (int j = 0; j < 2; ++j)
                    bq[j] = *(const f16x8*)&DhhP[
                        (size_t)(n0 + wn + j * 16 + lr) * Hsz + s * 32 + lkb * 8];
#pragma unroll
                for (int i = 0; i < 2; ++i)
#pragma unroll
                    for (int j = 0; j < 2; ++j)
                        acc[i][j] = __builtin_amdgcn_mfma_f32_16x16x32_f16(
                            asfrag(ah[i][s]), bq[j], acc[i][j], 0, 0, 0);
            }
        } else {
#pragma unroll
            for (int s = 0; s < 16; ++s) {
                f16x8 bq[2];
#pragma unroll
                for (int j = 0; j < 2; ++j) {
                    const int rb = wn + j * 16 + lr;
                    bq[j] = *(const f16x8*)&Bh[(s >> 1) * 4096 + rb * 64 +
                                               ((((s & 1) * 4 + lkb) ^ (rb & 7)) * 8)];
                }
#pragma unroll
                for (int i = 0; i < 2; ++i)
#pragma unroll
                    for (int j = 0; j < 2; ++j)
                        acc[i][j] = __builtin_amdgcn_mfma_f32_16x16x32_f16(
                            asfrag(ah[i][s]), bq[j], acc[i][j], 0, 0, 0);
            }
        }

        // ---- wave-local gate transpose (lgkmcnt only) ----
#pragma unroll
        for (int i = 0; i < 2; ++i)
#pragma unroll
            for (int j = 0; j < 2; ++j)
#pragma unroll
                for (int r = 0; r < 4; ++r)
                    xc[(i * 2 + j) * 272 + lr * 17 + lkb * 4 + r] = acc[i][j][r];
        asm volatile("s_waitcnt lgkmcnt(0)" ::: "memory");

#pragma unroll
        for (int i = 0; i < 2; ++i)
#pragma unroll
            for (int j = 0; j < 2; ++j) {
                const float gi = xc[(i * 2 + j) * 272 + (4 * lkb + 0) * 17 + lr];
                const float gf = xc[(i * 2 + j) * 272 + (4 * lkb + 1) * 17 + lr];
                const float gg = xc[(i * 2 + j) * 272 + (4 * lkb + 2) * 17 + lr];
                const float go = xc[(i * 2 + j) * 272 + (4 * lkb + 3) * 17 + lr];
                const float iv = sigm(gi), fv = sigm(gf);
                const float gv = tanh_f(gg), ov = sigm(go);
                const int q = i * 2 + j;
                const float cn = fv * cc[q] + iv * gv;
                cc[q] = cn;
                hxw[(i * 16 + lr) * 8 + j * 4 + lkb] = (f16)(ov * tanh_f(cn));
            }
        asm volatile("s_waitcnt lgkmcnt(0)" ::: "memory");

        // ---- h store: PLAIN 16B (write-through -> own XCD L2) ----
        if (lane < 32) {
            const int g = ny * 2 + (w >> 1);
            const int row = b0 + wm + (lane & 31);
            f16* dp = hdst + ((size_t)g * 512 + row) * 8;
            *(i32x4*)dp = *(const i32x4*)&hxw[(lane & 31) * 8];
        }

        // ---- drain (L2 ack), then per-wave flag (plain store, L2) ----
        asm volatile("s_waitcnt vmcnt(0)" ::: "memory");
        if (t < Tsz - 1 && lane == 0)
            fbase[(size_t)t * 128 + ny * 4 + w] = 1u;
    }

    if (ENC) {
        float4 cv = {cc[0], cc[1], cc[2], cc[3]};
        *(float4*)&cbuf[cbase] = cv;
    }
}

// ---------------------------------------------------------------------------
// z projection from the dec step buffers (R10-proven path).
// grid (1024, 4): blockIdx.x -> (b = x>>1, t0 = (x&1)*64).
// ---------------------------------------------------------------------------
__global__ __launch_bounds__(256, 2) void z_final(
    const f16* __restrict__ hb, const f16* __restrict__ zw,
    const float* __restrict__ zb, float* __restrict__ out)
{
    __shared__ f16 As[2][4096];
    __shared__ f16 Bs[2][4096];

    const int tid = threadIdx.x;
    const int lane = tid & 63, w = tid >> 6;
    const int lr = lane & 15, lkb = lane >> 4;
    const int wm = (w & 1) * 32, wn = (w >> 1) * 32;
    const int b  = blockIdx.x >> 1;
    const int t0 = (blockIdx.x & 1) * 64;
    const int n0 = blockIdx.y * 64;
    const int rl = lane >> 3, kcB = (lane & 7) * 8;
    const int axr = (lane & 7) ^ rl;   // pre-swizzled source chunk for As

    f32x4 acc[2][2];
#pragma unroll
    for (int j = 0; j < 2; ++j) {
        const float bv = zb[n0 + wn + j * 16 + lr];
        acc[0][j] = (f32x4){bv, bv, bv, bv};
        acc[1][j] = acc[0][j];
    }

    auto stage = [&](int buf, int kt) {
#pragma unroll
        for (int s2 = 0; s2 < 2; ++s2) {
            const int g = w + s2 * 4;
            const int trow = t0 + g * 8 + rl;     // this LDS row = time t
            gld16(hb + (size_t)trow * BUFE + ((size_t)(kt * 8 + axr) * 512 + b) * 8,
                  &As[buf][g * 512]);
            const int row = g * 8 + rl;
            gld16(zw + (size_t)(n0 + row) * Hsz + kt * 64 + kcB, &Bs[buf][g * 512]);
        }
    };

    stage(0, 0);
    int cur = 0;
    for (int kt = 0; kt < 8; ++kt) {
        asm volatile("s_waitcnt vmcnt(0)" ::: "memory");
        __syncthreads();
        if (kt + 1 < 8) stage(cur ^ 1, kt + 1);
        f16x8 af[2][2], bf[2][2];
#pragma unroll
        for (int i = 0; i < 2; ++i) {
            const int ra = wm + i * 16 + lr;
            const int rb = wn + i * 16 + lr;
#pragma unroll
            for (int ks = 0; ks < 2; ++ks) {
                af[i][ks] = *(const f16x8*)&As[cur][ra * 64 + (((ks * 4 + lkb) ^ (ra & 7)) * 8)];
                bf[i][ks] = *(const f16x8*)&Bs[cur][rb * 64 + (((ks * 4 + lkb) ^ (rb & 7)) * 8)];
            }
        }
#pragma unroll
        for (int ks = 0; ks < 2; ++ks)
#pragma unroll
            for (int i = 0; i < 2; ++i)
#pragma unroll
                for (int j = 0; j < 2; ++j)
                    acc[i][j] = __builtin_amdgcn_mfma_f32_16x16x32_f16(
                        af[i][ks], bf[j][ks], acc[i][j], 0, 0, 0);
        cur ^= 1;
    }
#pragma unroll
    for (int i = 0; i < 2; ++i)
#pragma unroll
        for (int j = 0; j < 2; ++j)
#pragma unroll
            for (int r = 0; r < 4; ++r) {
                const int t = t0 + wm + i * 16 + lkb * 4 + r;
                const int col = n0 + wn + j * 16 + lr;
                out[((size_t)b * Tsz + t) * Zsz + col] = tanh_f(acc[i][j][r]);
            }
}

// ---------------------------------------------------------------------------
extern "C" void kernel_launch(void* const* d_in, const int* in_sizes, int n_in,
                              void* d_out, int out_size, void* d_ws, size_t ws_size,
                              hipStream_t stream) {
    (void)in_sizes; (void)n_in; (void)out_size; (void)ws_size;
    const float* x        = (const float*)d_in[0];
    const float* enc_W_ih = (const float*)d_in[1];
    const float* enc_W_hh = (const float*)d_in[2];
    const float* enc_b_ih = (const float*)d_in[3];
    const float* enc_b_hh = (const float*)d_in[4];
    const float* dec_W_ih = (const float*)d_in[5];
    const float* dec_W_hh = (const float*)d_in[6];
    const float* dec_b_ih = (const float*)d_in[7];
    const float* dec_b_hh = (const float*)d_in[8];
    const float* z_W      = (const float*)d_in[9];
    const float* z_b      = (const float*)d_in[10];
    float* out = (float*)d_out;

    // flags: enc [0..131071], dec [131072..262143]; xcd ctrs [262144..262159]
    unsigned* flags = (unsigned*)d_ws;
    unsigned* ctrs  = flags + 262144;
    float* fp    = (float*)(ctrs + 16);
    float* encB  = fp;  fp += NG;
    float* decB  = fp;  fp += NG;
    float* decB0 = fp;  fp += NG;
    float* cbuf  = fp;  fp += 256 * 256 * 4;
    f16* hp    = (f16*)fp;
    f16* xe    = hp;  hp += (size_t)Bsz * Tsz * Esz;
    f16* eih_s = hp;  hp += (size_t)NG * Esz;
    f16* ehh_s = hp;  hp += (size_t)NG * Hsz;
    f16* dhh_p = hp;  hp += (size_t)NG * Hsz;
    f16* wsm_s = hp;  hp += (size_t)NG * Hsz;
    f16* zw_s  = hp;  hp += (size_t)Zsz * Hsz;
    f16* hb    = hp;  hp += (size_t)129 * BUFE;   // 129 step buffers

    prep_kernel<<<512, 256, 0, stream>>>(
        x, enc_W_ih, enc_W_hh, enc_b_ih, enc_b_hh,
        dec_W_ih, dec_W_hh, dec_b_ih, dec_b_hh, z_W,
        xe, eih_s, ehh_s, dhh_p, wsm_s, zw_s,
        encB, decB, decB0, hb, flags);

    persist_kernel<true><<<256, 256, 0, stream>>>(
        xe, eih_s, ehh_s, nullptr, encB, nullptr,
        hb, cbuf, flags, ctrs);

    persist_kernel<false><<<256, 256, 0, stream>>>(
        nullptr, nullptr, wsm_s, dhh_p, decB, decB0,
        hb, cbuf, flags + 131072, ctrs + 8);

    z_final<<<dim3(1024, 4), 256, 0, stream>>>(hb, zw_s, z_b, out);
}